// Round 7
// baseline (306.308 us; speedup 1.0000x reference)
//
#include <hip/hip_runtime.h>
#include <hip/hip_fp16.h>

#define D_ 1024

typedef __fp16   fp16x2 __attribute__((ext_vector_type(2)));
typedef _Float16 h4 __attribute__((ext_vector_type(4)));
typedef _Float16 h8 __attribute__((ext_vector_type(8)));
typedef float    f4 __attribute__((ext_vector_type(4)));

#define MFMA32(A, B, C) __builtin_amdgcn_mfma_f32_16x16x32_f16(A, B, C, 0, 0, 0)
#define MFMA16(A, B, C) __builtin_amdgcn_mfma_f32_16x16x16f16(A, B, C, 0, 0, 0)

// ---- pre-pass 1: Wi f32[4][256][80] + bi -> h8[st][rt 16][chunk 12][p16 16]
// chunks 0-9 real K, chunk 10 = [bias,0x7] (bias via B=e0), chunk 11 = 0
__global__ void prep_wi(const float* __restrict__ Wi, const float* __restrict__ bi,
                        h8* __restrict__ Wi16) {
    int t = blockIdx.x * 256 + threadIdx.x;
    if (t >= 4 * 16 * 12 * 16) return;
    int p16 = t & 15;
    int chunk = (t >> 4) % 12;
    int rt = ((t >> 4) / 12) & 15;
    int st = t / 3072;
    int r = rt * 16 + p16;
    h8 v = {0, 0, 0, 0, 0, 0, 0, 0};
    if (chunk < 10) {
        const float* s = Wi + ((size_t)(st * 256 + r) * 80 + chunk * 8);
#pragma unroll
        for (int j = 0; j < 8; ++j) v[j] = (_Float16)s[j];
    } else if (chunk == 10) {
        v[0] = (_Float16)bi[st * 256 + r];
    }
    Wi16[t] = v;
}

// ---- pre-pass 2: Wo f32[4][8][256] -> 16x16x16 A-frags h4[st][kc 8][s 2][lane 64]
// A2[row=c=p16][k16=q*4+j] = Wo[st][p16][kc*32+s*16+q*4+j], rows p16>=8 zero
__global__ void prep_wo(const float* __restrict__ Wo, h4* __restrict__ Wo2) {
    int t = blockIdx.x * 256 + threadIdx.x;
    if (t >= 4096) return;
    int lane = t & 63;
    int s = (t >> 6) & 1;
    int kc = (t >> 7) & 7;
    int st = t >> 10;
    int p16 = lane & 15, q = lane >> 4;
    h4 v = {0, 0, 0, 0};
    if (p16 < 8) {
        const float* src = Wo + ((size_t)(st * 8 + p16) * 256 + kc * 32 + s * 16 + q * 4);
#pragma unroll
        for (int j = 0; j < 4; ++j) v[j] = (_Float16)src[j];
    }
    Wo2[t] = v;
}

// Pade CF(5,4): tanh(x) ~= x(945+105u+u^2)/(945+420u+15u^2), u=x^2, clamp |x|<=3.5.
// Max err ~9.5e-4 over all R (verified at x=1,2,2.5,3,3.5 and saturation branch).
// 8 full-rate f32 VALU + 1 v_rcp_f32 per value; zero f16 transcendentals.
__device__ __forceinline__ float tanh_pade(float x) {
    float c = fmaxf(fminf(x, 3.5f), -3.5f);      // -> v_med3_f32
    float u = c * c;
    float num = c * fmaf(u + 105.f, u, 945.f);
    float den = fmaf(fmaf(u, 15.f, 420.f), u, 945.f);
    return num * __builtin_amdgcn_rcpf(den);
}

__device__ __forceinline__ h4 tanh4(const f4 a) {
    float t0 = tanh_pade(a[0]);
    float t1 = tanh_pade(a[1]);
    float t2 = tanh_pade(a[2]);
    float t3 = tanh_pade(a[3]);
    union { h4 v; fp16x2 h[2]; } u;
    u.h[0] = __builtin_amdgcn_cvt_pkrtz(t0, t1);
    u.h[1] = __builtin_amdgcn_cvt_pkrtz(t2, t3);
    return u.v;
}

// ---- main: 1 wave = 1 row; no barriers, no cross-lane H exchange.
// launch_bounds(256,2): grid gives 16 waves/CU (4/SIMD); VGPR must stay <=128
// for 4 waves/SIMD ((256,4) forced a 64-VGPR cap -> 800 MB spill; don't).
__global__ __launch_bounds__(256, 2) void ldrfm6(
    const float* __restrict__ x,    // [N,1024]
    const h8* __restrict__ Wi16,    // [4][16][12][16]
    const h4* __restrict__ Wo2,     // [4][8][2][64]
    float* __restrict__ out)        // [N,1024]
{
    // rings replicated so windows never wrap: slot s holds pair (s-2) mod 128; slots 0..131
    __shared__ h8 xr[4][136];
    __shared__ h8 zr[4][136];
    __shared__ h8 cpad[8][16];      // [pt][0]=e0 (bias col), [pt][1]=0 (K-pad)

    const int tid = threadIdx.x;
    const int w = tid >> 6, lane = tid & 63;
    const int p16 = lane & 15, q = lane >> 4;
    const int row = blockIdx.x * 4 + w;

    // every wave writes cpad (identical values -> benign; keeps it wave-synchronous)
    if (lane < 16) {
        h8 v = {0, 0, 0, 0, 0, 0, 0, 0};
        if ((lane & 1) == 0) v[0] = (_Float16)1.0f;
        cpad[lane >> 1][lane & 1] = v;
    }

    // load + convert own row -> x ring and z ring (z starts as x), with boundary replicas
    {
        const f4* xp = (const f4*)(x + (size_t)row * D_) + lane * 4;
        f4 v0 = xp[0], v1 = xp[1], v2 = xp[2], v3 = xp[3];
        union { h8 v; fp16x2 h[4]; } a, b;
        a.h[0] = __builtin_amdgcn_cvt_pkrtz(v0[0], v0[1]);
        a.h[1] = __builtin_amdgcn_cvt_pkrtz(v0[2], v0[3]);
        a.h[2] = __builtin_amdgcn_cvt_pkrtz(v1[0], v1[1]);
        a.h[3] = __builtin_amdgcn_cvt_pkrtz(v1[2], v1[3]);
        b.h[0] = __builtin_amdgcn_cvt_pkrtz(v2[0], v2[1]);
        b.h[1] = __builtin_amdgcn_cvt_pkrtz(v2[2], v2[3]);
        b.h[2] = __builtin_amdgcn_cvt_pkrtz(v3[0], v3[1]);
        b.h[3] = __builtin_amdgcn_cvt_pkrtz(v3[2], v3[3]);
        xr[w][2 * lane + 2] = a.v; xr[w][2 * lane + 3] = b.v;
        zr[w][2 * lane + 2] = a.v; zr[w][2 * lane + 3] = b.v;
        if (lane == 63) {          // pairs 126,127 -> slots 0,1
            xr[w][0] = a.v; xr[w][1] = b.v; zr[w][0] = a.v; zr[w][1] = b.v;
        }
        if (lane == 0) {           // pairs 0,1 -> slots 130,131
            xr[w][130] = a.v; xr[w][131] = b.v; zr[w][130] = a.v; zr[w][131] = b.v;
        }
    }

    // per-lane B-frag base addresses (fixed for whole kernel); pt adds offset pt*256
    const h8* b0p = &xr[w][p16 + q];                               // chunks 0-3 (x-window)
    const h8* b1p = (q == 0) ? &xr[w][p16 + 4]                     // chunk 4 (x)
                             : &zr[w][p16 + q - 1];                // chunks 5-7 (z)
    const h8* b2p = (q < 2) ? &zr[w][p16 + 3 + q]                  // chunks 8-9 (z)
                            : (const h8*)&cpad[0][q - 2];          // bias col / zero pad
    // z-write address (lanes q<2 own c-quad q*4..q*4+3 of pair p16 within each pt)
    _Float16* zwp = (_Float16*)&zr[w][p16 + 2] + q * 4;
    float* op = out + (size_t)row * D_ + p16 * 8 + q * 4;

    const f4 FZ = {0.f, 0.f, 0.f, 0.f};

#pragma unroll 1
    for (int st = 0; st < 4; ++st) {
        const h8* WiS = Wi16 + st * 3072;
        const h4* WoS = Wo2 + st * 1024;

        f4 acc2[8];
#pragma unroll
        for (int i = 0; i < 8; ++i) acc2[i] = FZ;

#pragma unroll 1
        for (int kc = 0; kc < 8; ++kc) {
            const h8* wp0 = WiS + ((2 * kc) * 12 + q) * 16 + p16;
            const h8* wp1 = WiS + ((2 * kc + 1) * 12 + q) * 16 + p16;
            h8 A00 = wp0[0], A01 = wp0[64], A02 = wp0[128];
            h8 A10 = wp1[0], A11 = wp1[64], A12 = wp1[128];
            h4 B20 = WoS[(kc * 2 + 0) * 64 + lane];
            h4 B21 = WoS[(kc * 2 + 1) * 64 + lane];

#pragma unroll
            for (int pt = 0; pt < 8; ++pt) {
                h8 b0 = *(const h8*)((const char*)b0p + pt * 256);
                h8 b1 = *(const h8*)((const char*)b1p + pt * 256);
                h8 b2 = *(const h8*)((const char*)b2p + pt * 256);
                f4 a0 = MFMA32(A00, b0, FZ);
                a0 = MFMA32(A01, b1, a0);
                a0 = MFMA32(A02, b2, a0);
                f4 a1 = MFMA32(A10, b0, FZ);
                a1 = MFMA32(A11, b1, a1);
                a1 = MFMA32(A12, b2, a1);
                h4 h0 = tanh4(a0);
                h4 h1 = tanh4(a1);
                acc2[pt] = MFMA16(B20, h0, acc2[pt]);
                acc2[pt] = MFMA16(B21, h1, acc2[pt]);
            }
        }

        if (st < 3) {
            // in-place z update: all window reads of this stage are already done
#pragma unroll
            for (int pt = 0; pt < 8; ++pt) {
                if (q < 2) {
                    union { h4 v; fp16x2 h[2]; } zv;
                    zv.h[0] = __builtin_amdgcn_cvt_pkrtz(acc2[pt][0], acc2[pt][1]);
                    zv.h[1] = __builtin_amdgcn_cvt_pkrtz(acc2[pt][2], acc2[pt][3]);
                    *(h4*)((char*)zwp + pt * 256) = zv.v;
                    if (pt == 0 && p16 < 2)                       // pairs 0,1 -> slots 130,131
                        *(h4*)((char*)zwp + pt * 256 + 2048) = zv.v;
                    if (pt == 7 && p16 >= 14)                     // pairs 126,127 -> slots 0,1
                        *(h4*)((char*)zwp + pt * 256 - 2048) = zv.v;
                }
            }
        } else {
#pragma unroll
            for (int pt = 0; pt < 8; ++pt) {
                if (q < 2) *(f4*)(op + pt * 128) = acc2[pt];
            }
        }
    }
}

extern "C" void kernel_launch(void* const* d_in, const int* in_sizes, int n_in,
                              void* d_out, int out_size, void* d_ws, size_t ws_size,
                              hipStream_t stream) {
    const float* x  = (const float*)d_in[0];
    const float* Wi = (const float*)d_in[1];
    const float* bi = (const float*)d_in[2];
    const float* Wo = (const float*)d_in[3];
    float* out = (float*)d_out;

    h8* Wi16 = (h8*)d_ws;                     // 12288 h8 = 192 KB
    h4* Wo2  = (h4*)(Wi16 + 12288);           // 4096 h4 = 32 KB

    prep_wi<<<48, 256, 0, stream>>>(Wi, bi, Wi16);
    prep_wo<<<16, 256, 0, stream>>>(Wo, Wo2);

    int nrows = in_sizes[0] / D_;             // 4096
    ldrfm6<<<nrows / 4, 256, 0, stream>>>(x, Wi16, Wo2, out);
}

// Round 8
// 208.821 us; speedup vs baseline: 1.4668x; 1.4668x over previous
//
#include <hip/hip_runtime.h>
#include <hip/hip_fp16.h>

#define D_ 1024
#define C2LOG2E 2.8853900817779268f   // 2*log2(e); pre-multiplied into Wi,bi

typedef __fp16   fp16x2 __attribute__((ext_vector_type(2)));
typedef _Float16 h4 __attribute__((ext_vector_type(4)));
typedef _Float16 h8 __attribute__((ext_vector_type(8)));
typedef float    f4 __attribute__((ext_vector_type(4)));

#define MFMA32(A, B, C) __builtin_amdgcn_mfma_f32_16x16x32_f16(A, B, C, 0, 0, 0)
#define MFMA16(A, B, C) __builtin_amdgcn_mfma_f32_16x16x16f16(A, B, C, 0, 0, 0)

// ---- merged pre-pass.
// part 1 (t<12288): Wi f32[4][256][80] + bi -> h8[st][rt 16][chunk 12][p16 16],
//   values PRE-SCALED by 2*log2(e) so GEMM1 outputs s=2log2e*(Wi.y+b) directly.
//   chunks 0-9 real K, chunk 10 = [C2*bias,0x7] (bias via B=e0), chunk 11 = 0.
// part 2: Wo f32[4][8][256] -> 16x16x16 A-frags h4[st][kc 8][s 2][lane 64] (unscaled).
__global__ void prep_all(const float* __restrict__ Wi, const float* __restrict__ bi,
                         const float* __restrict__ Wo,
                         h8* __restrict__ Wi16, h4* __restrict__ Wo2) {
    int t = blockIdx.x * 256 + threadIdx.x;
    if (t < 12288) {
        int p16 = t & 15;
        int chunk = (t >> 4) % 12;
        int rt = ((t >> 4) / 12) & 15;
        int st = t / 3072;
        int r = rt * 16 + p16;
        h8 v = {0, 0, 0, 0, 0, 0, 0, 0};
        if (chunk < 10) {
            const float* s = Wi + ((size_t)(st * 256 + r) * 80 + chunk * 8);
#pragma unroll
            for (int j = 0; j < 8; ++j) v[j] = (_Float16)(C2LOG2E * s[j]);
        } else if (chunk == 10) {
            v[0] = (_Float16)(C2LOG2E * bi[st * 256 + r]);
        }
        Wi16[t] = v;
    } else {
        int u = t - 12288;
        if (u >= 4096) return;
        int lane = u & 63;
        int s = (u >> 6) & 1;
        int kc = (u >> 7) & 7;
        int st = u >> 10;
        int p16 = lane & 15, q = lane >> 4;
        h4 v = {0, 0, 0, 0};
        if (p16 < 8) {
            const float* src = Wo + ((size_t)(st * 8 + p16) * 256 + kc * 32 + s * 16 + q * 4);
#pragma unroll
            for (int j = 0; j < 4; ++j) v[j] = (_Float16)src[j];
        }
        Wo2[u] = v;
    }
}

// tanh from pre-scaled s: tanh = 1 - 2/(1+2^s). 3 VALU + 4 trans per 2 values.
// Saturation via f16 special values: 2^(+big)=inf->rcp 0->+1; 2^(-big)=0->rcp(1)->-1.
// cvt_pkrtz clamps overflow to +-65504 (finite), so no explicit clamp needed.
__device__ __forceinline__ h4 tanh4(const f4 a) {
    const __half2 ONE  = __float2half2_rn(1.0f);
    const __half2 MTWO = __float2half2_rn(-2.0f);
    union { h4 v; fp16x2 h[2]; __half2 hh[2]; } u;
    u.h[0] = __builtin_amdgcn_cvt_pkrtz(a[0], a[1]);
    u.h[1] = __builtin_amdgcn_cvt_pkrtz(a[2], a[3]);
#pragma unroll
    for (int i = 0; i < 2; ++i) {
        __half2 e = h2exp2(u.hh[i]);
        __half2 r = h2rcp(__hadd2(e, ONE));
        u.hh[i] = __hfma2(r, MTWO, ONE);
    }
    return u.v;
}

// ---- main: 1 wave = 1 row; no barriers, no cross-lane H exchange.
// launch_bounds(256,2): grid gives 16 waves/CU (4/SIMD); VGPR must stay <=128
// for 4 waves/SIMD ((256,4) forced a 64-VGPR cap -> 800 MB spill; don't).
__global__ __launch_bounds__(256, 2) void ldrfm8(
    const float* __restrict__ x,    // [N,1024]
    const h8* __restrict__ Wi16,    // [4][16][12][16]
    const h4* __restrict__ Wo2,     // [4][8][2][64]
    float* __restrict__ out)        // [N,1024]
{
    // rings replicated so windows never wrap: slot s holds pair (s-2) mod 128; slots 0..131
    __shared__ h8 xr[4][136];
    __shared__ h8 zr[4][136];
    __shared__ h8 cpad[8][16];      // [pt][0]=e0 (bias col), [pt][1]=0 (K-pad)

    const int tid = threadIdx.x;
    const int w = tid >> 6, lane = tid & 63;
    const int p16 = lane & 15, q = lane >> 4;
    const int row = blockIdx.x * 4 + w;

    // every wave writes cpad (identical values -> benign; keeps it wave-synchronous)
    if (lane < 16) {
        h8 v = {0, 0, 0, 0, 0, 0, 0, 0};
        if ((lane & 1) == 0) v[0] = (_Float16)1.0f;
        cpad[lane >> 1][lane & 1] = v;
    }

    // load + convert own row -> x ring and z ring (z starts as x), with boundary replicas
    {
        const f4* xp = (const f4*)(x + (size_t)row * D_) + lane * 4;
        f4 v0 = xp[0], v1 = xp[1], v2 = xp[2], v3 = xp[3];
        union { h8 v; fp16x2 h[4]; } a, b;
        a.h[0] = __builtin_amdgcn_cvt_pkrtz(v0[0], v0[1]);
        a.h[1] = __builtin_amdgcn_cvt_pkrtz(v0[2], v0[3]);
        a.h[2] = __builtin_amdgcn_cvt_pkrtz(v1[0], v1[1]);
        a.h[3] = __builtin_amdgcn_cvt_pkrtz(v1[2], v1[3]);
        b.h[0] = __builtin_amdgcn_cvt_pkrtz(v2[0], v2[1]);
        b.h[1] = __builtin_amdgcn_cvt_pkrtz(v2[2], v2[3]);
        b.h[2] = __builtin_amdgcn_cvt_pkrtz(v3[0], v3[1]);
        b.h[3] = __builtin_amdgcn_cvt_pkrtz(v3[2], v3[3]);
        xr[w][2 * lane + 2] = a.v; xr[w][2 * lane + 3] = b.v;
        zr[w][2 * lane + 2] = a.v; zr[w][2 * lane + 3] = b.v;
        if (lane == 63) {          // pairs 126,127 -> slots 0,1
            xr[w][0] = a.v; xr[w][1] = b.v; zr[w][0] = a.v; zr[w][1] = b.v;
        }
        if (lane == 0) {           // pairs 0,1 -> slots 130,131
            xr[w][130] = a.v; xr[w][131] = b.v; zr[w][130] = a.v; zr[w][131] = b.v;
        }
    }

    // per-lane B-frag base addresses (fixed for whole kernel); pt adds offset pt*256
    const h8* b0p = &xr[w][p16 + q];                               // chunks 0-3 (x-window)
    const h8* b1p = (q == 0) ? &xr[w][p16 + 4]                     // chunk 4 (x)
                             : &zr[w][p16 + q - 1];                // chunks 5-7 (z)
    const h8* b2p = (q < 2) ? &zr[w][p16 + 3 + q]                  // chunks 8-9 (z)
                            : (const h8*)&cpad[0][q - 2];          // bias col / zero pad
    // z-write address (lanes q<2 own c-quad q*4..q*4+3 of pair p16 within each pt)
    _Float16* zwp = (_Float16*)&zr[w][p16 + 2] + q * 4;
    float* op = out + (size_t)row * D_ + p16 * 8 + q * 4;

    const f4 FZ = {0.f, 0.f, 0.f, 0.f};

#pragma unroll 1
    for (int st = 0; st < 4; ++st) {
        const h8* WiS = Wi16 + st * 3072;
        const h4* WoS = Wo2 + st * 1024;

        f4 acc2[8];
#pragma unroll
        for (int i = 0; i < 8; ++i) acc2[i] = FZ;

#pragma unroll 1
        for (int kc = 0; kc < 8; ++kc) {
            const h8* wp0 = WiS + ((2 * kc) * 12 + q) * 16 + p16;
            const h8* wp1 = WiS + ((2 * kc + 1) * 12 + q) * 16 + p16;
            h8 A00 = wp0[0], A01 = wp0[64], A02 = wp0[128];
            h8 A10 = wp1[0], A11 = wp1[64], A12 = wp1[128];
            h4 B20 = WoS[(kc * 2 + 0) * 64 + lane];
            h4 B21 = WoS[(kc * 2 + 1) * 64 + lane];

#pragma unroll
            for (int pt = 0; pt < 8; ++pt) {
                h8 b0 = *(const h8*)((const char*)b0p + pt * 256);
                h8 b1 = *(const h8*)((const char*)b1p + pt * 256);
                h8 b2 = *(const h8*)((const char*)b2p + pt * 256);
                f4 a0 = MFMA32(A00, b0, FZ);
                a0 = MFMA32(A01, b1, a0);
                a0 = MFMA32(A02, b2, a0);
                f4 a1 = MFMA32(A10, b0, FZ);
                a1 = MFMA32(A11, b1, a1);
                a1 = MFMA32(A12, b2, a1);
                h4 h0 = tanh4(a0);
                h4 h1 = tanh4(a1);
                acc2[pt] = MFMA16(B20, h0, acc2[pt]);
                acc2[pt] = MFMA16(B21, h1, acc2[pt]);
            }
        }

        if (st < 3) {
            // in-place z update: all window reads of this stage are already done
#pragma unroll
            for (int pt = 0; pt < 8; ++pt) {
                if (q < 2) {
                    union { h4 v; fp16x2 h[2]; } zv;
                    zv.h[0] = __builtin_amdgcn_cvt_pkrtz(acc2[pt][0], acc2[pt][1]);
                    zv.h[1] = __builtin_amdgcn_cvt_pkrtz(acc2[pt][2], acc2[pt][3]);
                    *(h4*)((char*)zwp + pt * 256) = zv.v;
                    if (pt == 0 && p16 < 2)                       // pairs 0,1 -> slots 130,131
                        *(h4*)((char*)zwp + pt * 256 + 2048) = zv.v;
                    if (pt == 7 && p16 >= 14)                     // pairs 126,127 -> slots 0,1
                        *(h4*)((char*)zwp + pt * 256 - 2048) = zv.v;
                }
            }
        } else {
#pragma unroll
            for (int pt = 0; pt < 8; ++pt) {
                if (q < 2) *(f4*)(op + pt * 128) = acc2[pt];
            }
        }
    }
}

extern "C" void kernel_launch(void* const* d_in, const int* in_sizes, int n_in,
                              void* d_out, int out_size, void* d_ws, size_t ws_size,
                              hipStream_t stream) {
    const float* x  = (const float*)d_in[0];
    const float* Wi = (const float*)d_in[1];
    const float* bi = (const float*)d_in[2];
    const float* Wo = (const float*)d_in[3];
    float* out = (float*)d_out;

    h8* Wi16 = (h8*)d_ws;                     // 12288 h8 = 192 KB
    h4* Wo2  = (h4*)(Wi16 + 12288);           // 4096 h4 = 32 KB

    prep_all<<<64, 256, 0, stream>>>(Wi, bi, Wo, Wi16, Wo2);

    int nrows = in_sizes[0] / D_;             // 4096
    ldrfm8<<<nrows / 4, 256, 0, stream>>>(x, Wi16, Wo2, out);
}